// Round 6
// baseline (93.939 us; speedup 1.0000x reference)
//
#include <hip/hip_runtime.h>
#include <hip/hip_bf16.h>

#define S_ 1024
#define E_ 768
#define H_ 12

typedef __bf16  bf16x8 __attribute__((ext_vector_type(8)));
typedef float   f32x4  __attribute__((ext_vector_type(4)));
typedef unsigned short u16x8 __attribute__((ext_vector_type(8)));
typedef unsigned short u16x4 __attribute__((ext_vector_type(4)));

__device__ __forceinline__ unsigned short f2bf(float f) {
    union { float f; unsigned u; } a; a.f = f;
    unsigned u = a.u;
    u += 0x7FFFu + ((u >> 16) & 1u);   // RNE
    return (unsigned short)(u >> 16);
}

__device__ __forceinline__ u16x8 pack8(float4 a, float4 b, float w) {
    u16x8 o;
    o[0] = f2bf(a.x * w); o[1] = f2bf(a.y * w); o[2] = f2bf(a.z * w); o[3] = f2bf(a.w * w);
    o[4] = f2bf(b.x * w); o[5] = f2bf(b.y * w); o[6] = f2bf(b.z * w); o[7] = f2bf(b.w * w);
    return o;
}

// LDS tile layout: R rows x 64 bf16 (128B/row, 8x16B chunks).
// Physical chunk (row, cb) holds global chunk (row, cb ^ (row&7)).
__device__ __forceinline__ bf16x8 ld_frag(const char* lbase, int row, int kk, int lane) {
    int cbyte = (kk * 64 + ((lane >> 4) * 16)) ^ ((row & 7) << 4);
    return *(const bf16x8*)(lbase + row * 128 + cbyte);
}

// ---------------- proj: P[m,n] = sum_k X[m,k]*W[n,k]*scale_n + bias_n, bf16 out ----------------
__global__ __launch_bounds__(256) void proj_kernel(
    const float* __restrict__ q_in, const float* __restrict__ k_in,
    const float* __restrict__ Wq, const float* __restrict__ Wk,
    const float* __restrict__ bq, const float* __restrict__ bk,
    const float* __restrict__ lin_w,
    unsigned short* __restrict__ qs, unsigned short* __restrict__ kp)
{
    __shared__ char lds[32768];   // Xb0 Xb1 Wb0 Wb1, 8KB each

    const float* X    = blockIdx.z ? k_in : q_in;
    const float* W    = blockIdx.z ? Wk   : Wq;
    const float* bias = blockIdx.z ? bk   : bq;
    unsigned short* P = blockIdx.z ? kp   : qs;
    const float invs = 0.35355339059327373f; // 1/sqrt(8)

    int tid = threadIdx.x, lane = tid & 63, wid = tid >> 6;
    int wn = wid >> 1, wm = wid & 1;
    int tm = blockIdx.y * 64, tn = blockIdx.x * 64;

    int c0 = tid,        r0 = c0 >> 3, g0 = ((c0 & 7) ^ (r0 & 7)) * 8;
    int c1 = 256 + tid,  r1 = c1 >> 3, g1 = ((c1 & 7) ^ (r1 & 7)) * 8;
    float sw0 = 1.0f, sw1 = 1.0f;                 // W row scale (q side folds lin_w)
    if (blockIdx.z == 0) { sw0 = lin_w[r0 >> 3] * invs; sw1 = lin_w[r1 >> 3] * invs; }

    const float* Xg = X + (size_t)tm * E_;
    const float* Wg = W + (size_t)tn * E_;

    float4 xv0, xv1, xv2, xv3, wv0, wv1, wv2, wv3;
#define LOADXW(kb) { \
    const float* xs0 = Xg + r0 * E_ + (kb) + g0; xv0 = *(const float4*)xs0; xv1 = *(const float4*)(xs0 + 4); \
    const float* xs1 = Xg + r1 * E_ + (kb) + g1; xv2 = *(const float4*)xs1; xv3 = *(const float4*)(xs1 + 4); \
    const float* ws0 = Wg + r0 * E_ + (kb) + g0; wv0 = *(const float4*)ws0; wv1 = *(const float4*)(ws0 + 4); \
    const float* ws1 = Wg + r1 * E_ + (kb) + g1; wv2 = *(const float4*)ws1; wv3 = *(const float4*)(ws1 + 4); }
#define WRITEXW(buf) { \
    char* xb = lds + (buf) * 8192; \
    *(u16x8*)(xb + c0 * 16) = pack8(xv0, xv1, 1.0f); \
    *(u16x8*)(xb + c1 * 16) = pack8(xv2, xv3, 1.0f); \
    char* wb = lds + 16384 + (buf) * 8192; \
    *(u16x8*)(wb + c0 * 16) = pack8(wv0, wv1, sw0); \
    *(u16x8*)(wb + c1 * 16) = pack8(wv2, wv3, sw1); }

    f32x4 acc[2][2];
#pragma unroll
    for (int nj = 0; nj < 2; ++nj) {
        int n0 = tn + wn * 32 + nj * 16 + ((lane >> 4) << 2);
        float4 b4 = *(const float4*)(bias + n0);
        float w = (blockIdx.z == 0) ? lin_w[(n0 & 63) >> 3] * invs : 1.0f;
#pragma unroll
        for (int mi = 0; mi < 2; ++mi)
            acc[nj][mi] = f32x4{b4.x * w, b4.y * w, b4.z * w, b4.w * w};
    }

#define COMPSTEP(buf) { \
    const char* Xc = lds + (buf) * 8192; \
    const char* Wc = lds + 16384 + (buf) * 8192; \
    _Pragma("unroll") \
    for (int kk = 0; kk < 2; ++kk) { \
        bf16x8 a0 = ld_frag(Wc, wn * 32 + (lane & 15), kk, lane); \
        bf16x8 a1 = ld_frag(Wc, wn * 32 + 16 + (lane & 15), kk, lane); \
        bf16x8 b0 = ld_frag(Xc, wm * 32 + (lane & 15), kk, lane); \
        bf16x8 b1 = ld_frag(Xc, wm * 32 + 16 + (lane & 15), kk, lane); \
        acc[0][0] = __builtin_amdgcn_mfma_f32_16x16x32_bf16(a0, b0, acc[0][0], 0, 0, 0); \
        acc[0][1] = __builtin_amdgcn_mfma_f32_16x16x32_bf16(a0, b1, acc[0][1], 0, 0, 0); \
        acc[1][0] = __builtin_amdgcn_mfma_f32_16x16x32_bf16(a1, b0, acc[1][0], 0, 0, 0); \
        acc[1][1] = __builtin_amdgcn_mfma_f32_16x16x32_bf16(a1, b1, acc[1][1], 0, 0, 0); \
    } }

    LOADXW(0);
    WRITEXW(0);
    __syncthreads();
    int cur = 0;
#pragma unroll 2
    for (int t = 0; t < 11; ++t) {
        LOADXW((t + 1) * 64);
        COMPSTEP(cur);
        WRITEXW(cur ^ 1);
        __syncthreads();
        cur ^= 1;
    }
    COMPSTEP(cur);

#pragma unroll
    for (int nj = 0; nj < 2; ++nj)
#pragma unroll
        for (int mi = 0; mi < 2; ++mi) {
            int n0 = tn + wn * 32 + nj * 16 + ((lane >> 4) << 2);
            int m  = tm + wm * 32 + mi * 16 + (lane & 15);
            u16x4 pk;
            pk[0] = f2bf(acc[nj][mi][0]); pk[1] = f2bf(acc[nj][mi][1]);
            pk[2] = f2bf(acc[nj][mi][2]); pk[3] = f2bf(acc[nj][mi][3]);
            *(u16x4*)(P + (size_t)m * E_ + n0) = pk;
        }
#undef LOADXW
#undef WRITEXW
#undef COMPSTEP
}

// ---------------- scores: per (b,h): out[i,j] = qs_i . kp_j + lin_b, fp32 out ----------------
__global__ __launch_bounds__(256) void scores_kernel(
    const unsigned short* __restrict__ qs, const unsigned short* __restrict__ kp,
    const float* __restrict__ lin_b, float* __restrict__ out)
{
    __shared__ char lds[32768];   // Kb0, Kb1: 16KB each (128 rows x 64 bf16)

    int z = blockIdx.z, b = z / H_, h = z - b * H_;
    int tid = threadIdx.x, lane = tid & 63, wid = tid >> 6;
    int wj = wid >> 1, wi = wid & 1;
    int ti = blockIdx.y * 128, tj = blockIdx.x * 256;

    const unsigned short* Qg = qs + (size_t)(b * S_) * E_ + h * 64;
    const unsigned short* Kg = kp + (size_t)(b * S_) * E_ + h * 64;

#define STAGEK(jbase, buf) { \
    char* lb = lds + (buf) * 16384; \
    _Pragma("unroll") \
    for (int pass = 0; pass < 4; ++pass) { \
        int c = pass * 256 + tid; \
        int row = c >> 3, cbg = (c & 7) ^ (row & 7); \
        __builtin_amdgcn_global_load_lds( \
            (const __attribute__((address_space(1))) void*)(Kg + (size_t)((jbase) + row) * E_ + cbg * 8), \
            (__attribute__((address_space(3))) void*)(lb + c * 16), 16, 0, 0); \
    } }

    bf16x8 qf[2][4];
    int qrow = ti + wi * 64 + (lane & 15);
#pragma unroll
    for (int ni = 0; ni < 4; ++ni)
#pragma unroll
        for (int kk = 0; kk < 2; ++kk)
            qf[kk][ni] = *(const bf16x8*)(Qg + (size_t)(qrow + ni * 16) * E_ + kk * 32 + ((lane >> 4) * 8));

    float lb0 = lin_b[0];
    float* O = out + ((size_t)z << 20);

    STAGEK(tj, 0);
    __syncthreads();
    STAGEK(tj + 128, 1);

#pragma unroll
    for (int sub = 0; sub < 2; ++sub) {
        f32x4 acc[4][4];
#pragma unroll
        for (int mj = 0; mj < 4; ++mj)
#pragma unroll
            for (int ni = 0; ni < 4; ++ni) acc[mj][ni] = f32x4{lb0, lb0, lb0, lb0};

        const char* Kc = lds + sub * 16384;
#pragma unroll
        for (int kk = 0; kk < 2; ++kk) {
            bf16x8 a[4];
#pragma unroll
            for (int mj = 0; mj < 4; ++mj) a[mj] = ld_frag(Kc, wj * 64 + mj * 16 + (lane & 15), kk, lane);
#pragma unroll
            for (int mj = 0; mj < 4; ++mj)
#pragma unroll
                for (int ni = 0; ni < 4; ++ni)
                    acc[mj][ni] = __builtin_amdgcn_mfma_f32_16x16x32_bf16(a[mj], qf[kk][ni], acc[mj][ni], 0, 0, 0);
        }

#pragma unroll
        for (int mj = 0; mj < 4; ++mj)
#pragma unroll
            for (int ni = 0; ni < 4; ++ni) {
                int i  = ti + wi * 64 + ni * 16 + (lane & 15);
                int j0 = tj + sub * 128 + wj * 64 + mj * 16 + ((lane >> 4) << 2);
                *(f32x4*)(O + (size_t)i * S_ + j0) = acc[mj][ni];
            }

        if (sub == 0) __syncthreads();
    }
#undef STAGEK
}

extern "C" void kernel_launch(void* const* d_in, const int* in_sizes, int n_in,
                              void* d_out, int out_size, void* d_ws, size_t ws_size,
                              hipStream_t stream)
{
    const float* k_in  = (const float*)d_in[0];
    const float* q_in  = (const float*)d_in[1];
    const float* Wq_w  = (const float*)d_in[2];
    const float* Wq_b  = (const float*)d_in[3];
    const float* Wk_w  = (const float*)d_in[4];
    const float* Wk_b  = (const float*)d_in[5];
    const float* lin_w = (const float*)d_in[6];
    const float* lin_b = (const float*)d_in[7];
    float* out = (float*)d_out;

    char* ws = (char*)d_ws;
    unsigned short* qsb = (unsigned short*)(ws + 0);
    unsigned short* kpb = (unsigned short*)(ws + 3145728);

    // ===== MEASUREMENT ROUND: each kernel launched TWICE (idempotent rewrites of the
    // same buffers; output unchanged). P+S = dur - 50.0 (R3 baseline); separates
    // fixed per-replay overhead from real kernel time. =====
    proj_kernel<<<dim3(12, 32, 2), dim3(256), 0, stream>>>(q_in, k_in, Wq_w, Wk_w, Wq_b, Wk_b, lin_w, qsb, kpb);
    proj_kernel<<<dim3(12, 32, 2), dim3(256), 0, stream>>>(q_in, k_in, Wq_w, Wk_w, Wq_b, Wk_b, lin_w, qsb, kpb);
    scores_kernel<<<dim3(4, 8, 24), dim3(256), 0, stream>>>(qsb, kpb, lin_b, out);
    scores_kernel<<<dim3(4, 8, 24), dim3(256), 0, stream>>>(qsb, kpb, lin_b, out);
}

// Round 7
// 71.651 us; speedup vs baseline: 1.3111x; 1.3111x over previous
//
#include <hip/hip_runtime.h>
#include <hip/hip_bf16.h>

#define S_ 1024
#define E_ 768
#define H_ 12

typedef __bf16  bf16x8 __attribute__((ext_vector_type(8)));
typedef float   f32x4  __attribute__((ext_vector_type(4)));
typedef unsigned short u16x8 __attribute__((ext_vector_type(8)));
typedef unsigned short u16x4 __attribute__((ext_vector_type(4)));

__device__ __forceinline__ unsigned short f2bf(float f) {
    union { float f; unsigned u; } a; a.f = f;
    unsigned u = a.u;
    u += 0x7FFFu + ((u >> 16) & 1u);   // RNE
    return (unsigned short)(u >> 16);
}

__device__ __forceinline__ u16x8 pack8(float4 a, float4 b, float w) {
    u16x8 o;
    o[0] = f2bf(a.x * w); o[1] = f2bf(a.y * w); o[2] = f2bf(a.z * w); o[3] = f2bf(a.w * w);
    o[4] = f2bf(b.x * w); o[5] = f2bf(b.y * w); o[6] = f2bf(b.z * w); o[7] = f2bf(b.w * w);
    return o;
}

// LDS tile layout: R rows x 64 bf16 (128B/row, 8x16B chunks).
// Physical chunk (row, cb) holds global chunk (row, cb ^ (row&7)).
__device__ __forceinline__ bf16x8 ld_frag(const char* lbase, int row, int kk, int lane) {
    int cbyte = (kk * 64 + ((lane >> 4) * 16)) ^ ((row & 7) << 4);
    return *(const bf16x8*)(lbase + row * 128 + cbyte);
}

// ---------------- proj: P[m,n] = sum_k X[m,k]*W[n,k]*scale_n + bias_n, bf16 out ----------------
__global__ __launch_bounds__(256) void proj_kernel(
    const float* __restrict__ q_in, const float* __restrict__ k_in,
    const float* __restrict__ Wq, const float* __restrict__ Wk,
    const float* __restrict__ bq, const float* __restrict__ bk,
    const float* __restrict__ lin_w,
    unsigned short* __restrict__ qs, unsigned short* __restrict__ kp)
{
    __shared__ char lds[32768];   // Xb0 Xb1 Wb0 Wb1, 8KB each

    const float* X    = blockIdx.z ? k_in : q_in;
    const float* W    = blockIdx.z ? Wk   : Wq;
    const float* bias = blockIdx.z ? bk   : bq;
    unsigned short* P = blockIdx.z ? kp   : qs;
    const float invs = 0.35355339059327373f; // 1/sqrt(8)

    int tid = threadIdx.x, lane = tid & 63, wid = tid >> 6;
    int wn = wid >> 1, wm = wid & 1;
    int tm = blockIdx.y * 64, tn = blockIdx.x * 64;

    int c0 = tid,        r0 = c0 >> 3, g0 = ((c0 & 7) ^ (r0 & 7)) * 8;
    int c1 = 256 + tid,  r1 = c1 >> 3, g1 = ((c1 & 7) ^ (r1 & 7)) * 8;
    float sw0 = 1.0f, sw1 = 1.0f;                 // W row scale (q side folds lin_w)
    if (blockIdx.z == 0) { sw0 = lin_w[r0 >> 3] * invs; sw1 = lin_w[r1 >> 3] * invs; }

    const float* Xg = X + (size_t)tm * E_;
    const float* Wg = W + (size_t)tn * E_;

    float4 xv0, xv1, xv2, xv3, wv0, wv1, wv2, wv3;
#define LOADXW(kb) { \
    const float* xs0 = Xg + r0 * E_ + (kb) + g0; xv0 = *(const float4*)xs0; xv1 = *(const float4*)(xs0 + 4); \
    const float* xs1 = Xg + r1 * E_ + (kb) + g1; xv2 = *(const float4*)xs1; xv3 = *(const float4*)(xs1 + 4); \
    const float* ws0 = Wg + r0 * E_ + (kb) + g0; wv0 = *(const float4*)ws0; wv1 = *(const float4*)(ws0 + 4); \
    const float* ws1 = Wg + r1 * E_ + (kb) + g1; wv2 = *(const float4*)ws1; wv3 = *(const float4*)(ws1 + 4); }
#define WRITEXW(buf) { \
    char* xb = lds + (buf) * 8192; \
    *(u16x8*)(xb + c0 * 16) = pack8(xv0, xv1, 1.0f); \
    *(u16x8*)(xb + c1 * 16) = pack8(xv2, xv3, 1.0f); \
    char* wb = lds + 16384 + (buf) * 8192; \
    *(u16x8*)(wb + c0 * 16) = pack8(wv0, wv1, sw0); \
    *(u16x8*)(wb + c1 * 16) = pack8(wv2, wv3, sw1); }

    f32x4 acc[2][2];
#pragma unroll
    for (int nj = 0; nj < 2; ++nj) {
        int n0 = tn + wn * 32 + nj * 16 + ((lane >> 4) << 2);
        float4 b4 = *(const float4*)(bias + n0);
        float w = (blockIdx.z == 0) ? lin_w[(n0 & 63) >> 3] * invs : 1.0f;
#pragma unroll
        for (int mi = 0; mi < 2; ++mi)
            acc[nj][mi] = f32x4{b4.x * w, b4.y * w, b4.z * w, b4.w * w};
    }

#define COMPSTEP(buf) { \
    const char* Xc = lds + (buf) * 8192; \
    const char* Wc = lds + 16384 + (buf) * 8192; \
    _Pragma("unroll") \
    for (int kk = 0; kk < 2; ++kk) { \
        bf16x8 a0 = ld_frag(Wc, wn * 32 + (lane & 15), kk, lane); \
        bf16x8 a1 = ld_frag(Wc, wn * 32 + 16 + (lane & 15), kk, lane); \
        bf16x8 b0 = ld_frag(Xc, wm * 32 + (lane & 15), kk, lane); \
        bf16x8 b1 = ld_frag(Xc, wm * 32 + 16 + (lane & 15), kk, lane); \
        acc[0][0] = __builtin_amdgcn_mfma_f32_16x16x32_bf16(a0, b0, acc[0][0], 0, 0, 0); \
        acc[0][1] = __builtin_amdgcn_mfma_f32_16x16x32_bf16(a0, b1, acc[0][1], 0, 0, 0); \
        acc[1][0] = __builtin_amdgcn_mfma_f32_16x16x32_bf16(a1, b0, acc[1][0], 0, 0, 0); \
        acc[1][1] = __builtin_amdgcn_mfma_f32_16x16x32_bf16(a1, b1, acc[1][1], 0, 0, 0); \
    } }

    LOADXW(0);
    WRITEXW(0);
    __syncthreads();
    int cur = 0;
#pragma unroll 2
    for (int t = 0; t < 11; ++t) {
        LOADXW((t + 1) * 64);
        COMPSTEP(cur);
        WRITEXW(cur ^ 1);
        __syncthreads();
        cur ^= 1;
    }
    COMPSTEP(cur);

#pragma unroll
    for (int nj = 0; nj < 2; ++nj)
#pragma unroll
        for (int mi = 0; mi < 2; ++mi) {
            int n0 = tn + wn * 32 + nj * 16 + ((lane >> 4) << 2);
            int m  = tm + wm * 32 + mi * 16 + (lane & 15);
            u16x4 pk;
            pk[0] = f2bf(acc[nj][mi][0]); pk[1] = f2bf(acc[nj][mi][1]);
            pk[2] = f2bf(acc[nj][mi][2]); pk[3] = f2bf(acc[nj][mi][3]);
            *(u16x4*)(P + (size_t)m * E_ + n0) = pk;
        }
#undef LOADXW
#undef WRITEXW
#undef COMPSTEP
}

// ---------------- scores: per (b,h): out[i,j] = qs_i . kp_j + lin_b, fp32 out ----------------
__global__ __launch_bounds__(256) void scores_kernel(
    const unsigned short* __restrict__ qs, const unsigned short* __restrict__ kp,
    const float* __restrict__ lin_b, float* __restrict__ out)
{
    __shared__ char lds[32768];   // Kb0, Kb1: 16KB each (128 rows x 64 bf16)

    int z = blockIdx.z, b = z / H_, h = z - b * H_;
    int tid = threadIdx.x, lane = tid & 63, wid = tid >> 6;
    int wj = wid >> 1, wi = wid & 1;
    int ti = blockIdx.y * 128, tj = blockIdx.x * 256;

    const unsigned short* Qg = qs + (size_t)(b * S_) * E_ + h * 64;
    const unsigned short* Kg = kp + (size_t)(b * S_) * E_ + h * 64;

#define STAGEK(jbase, buf) { \
    char* lb = lds + (buf) * 16384; \
    _Pragma("unroll") \
    for (int pass = 0; pass < 4; ++pass) { \
        int c = pass * 256 + tid; \
        int row = c >> 3, cbg = (c & 7) ^ (row & 7); \
        __builtin_amdgcn_global_load_lds( \
            (const __attribute__((address_space(1))) void*)(Kg + (size_t)((jbase) + row) * E_ + cbg * 8), \
            (__attribute__((address_space(3))) void*)(lb + c * 16), 16, 0, 0); \
    } }

    bf16x8 qf[2][4];
    int qrow = ti + wi * 64 + (lane & 15);
#pragma unroll
    for (int ni = 0; ni < 4; ++ni)
#pragma unroll
        for (int kk = 0; kk < 2; ++kk)
            qf[kk][ni] = *(const bf16x8*)(Qg + (size_t)(qrow + ni * 16) * E_ + kk * 32 + ((lane >> 4) * 8));

    float lb0 = lin_b[0];
    float* O = out + ((size_t)z << 20);

    STAGEK(tj, 0);
    __syncthreads();
    STAGEK(tj + 128, 1);

#pragma unroll
    for (int sub = 0; sub < 2; ++sub) {
        f32x4 acc[4][4];
#pragma unroll
        for (int mj = 0; mj < 4; ++mj)
#pragma unroll
            for (int ni = 0; ni < 4; ++ni) acc[mj][ni] = f32x4{lb0, lb0, lb0, lb0};

        const char* Kc = lds + sub * 16384;
#pragma unroll
        for (int kk = 0; kk < 2; ++kk) {
            bf16x8 a[4];
#pragma unroll
            for (int mj = 0; mj < 4; ++mj) a[mj] = ld_frag(Kc, wj * 64 + mj * 16 + (lane & 15), kk, lane);
#pragma unroll
            for (int mj = 0; mj < 4; ++mj)
#pragma unroll
                for (int ni = 0; ni < 4; ++ni)
                    acc[mj][ni] = __builtin_amdgcn_mfma_f32_16x16x32_bf16(a[mj], qf[kk][ni], acc[mj][ni], 0, 0, 0);
        }

#pragma unroll
        for (int mj = 0; mj < 4; ++mj)
#pragma unroll
            for (int ni = 0; ni < 4; ++ni) {
                int i  = ti + wi * 64 + ni * 16 + (lane & 15);
                int j0 = tj + sub * 128 + wj * 64 + mj * 16 + ((lane >> 4) << 2);
                *(f32x4*)(O + (size_t)i * S_ + j0) = acc[mj][ni];
            }

        if (sub == 0) __syncthreads();
    }
#undef STAGEK
}

extern "C" void kernel_launch(void* const* d_in, const int* in_sizes, int n_in,
                              void* d_out, int out_size, void* d_ws, size_t ws_size,
                              hipStream_t stream)
{
    const float* k_in  = (const float*)d_in[0];
    const float* q_in  = (const float*)d_in[1];
    const float* Wq_w  = (const float*)d_in[2];
    const float* Wq_b  = (const float*)d_in[3];
    const float* Wk_w  = (const float*)d_in[4];
    const float* Wk_b  = (const float*)d_in[5];
    const float* lin_w = (const float*)d_in[6];
    const float* lin_b = (const float*)d_in[7];
    float* out = (float*)d_out;

    char* ws = (char*)d_ws;
    unsigned short* qsb = (unsigned short*)(ws + 0);
    unsigned short* kpb = (unsigned short*)(ws + 3145728);

    // ===== MEASUREMENT ROUND 2: proj x1, scores x2 (idempotent).
    // R3: P+S+ovh = 50.0; R6: 2P+2S+ovh = 93.9 => ovh=6.1, P+S=43.9.
    // Here: dur = P + 2S + ovh = 50.0 + S  =>  S = dur - 50.0 exactly. =====
    proj_kernel<<<dim3(12, 32, 2), dim3(256), 0, stream>>>(q_in, k_in, Wq_w, Wk_w, Wq_b, Wk_b, lin_w, qsb, kpb);
    scores_kernel<<<dim3(4, 8, 24), dim3(256), 0, stream>>>(qsb, kpb, lin_b, out);
    scores_kernel<<<dim3(4, 8, 24), dim3(256), 0, stream>>>(qsb, kpb, lin_b, out);
}

// Round 8
// 45.339 us; speedup vs baseline: 2.0719x; 1.5803x over previous
//
#include <hip/hip_runtime.h>
#include <hip/hip_bf16.h>

#define S_ 1024
#define E_ 768
#define H_ 12

typedef __bf16  bf16x8 __attribute__((ext_vector_type(8)));
typedef float   f32x4  __attribute__((ext_vector_type(4)));
typedef unsigned short u16x8 __attribute__((ext_vector_type(8)));
typedef unsigned short u16x4 __attribute__((ext_vector_type(4)));

__device__ __forceinline__ unsigned short f2bf(float f) {
    union { float f; unsigned u; } a; a.f = f;
    unsigned u = a.u;
    u += 0x7FFFu + ((u >> 16) & 1u);   // RNE
    return (unsigned short)(u >> 16);
}

__device__ __forceinline__ u16x8 pack8(float4 a, float4 b) {
    u16x8 o;
    o[0] = f2bf(a.x); o[1] = f2bf(a.y); o[2] = f2bf(a.z); o[3] = f2bf(a.w);
    o[4] = f2bf(b.x); o[5] = f2bf(b.y); o[6] = f2bf(b.z); o[7] = f2bf(b.w);
    return o;
}

// LDS tile layout: R rows x 64 bf16 (128B/row, 8x16B chunks).
// Physical chunk (row, cb) holds global chunk (row, cb ^ (row&7)).
__device__ __forceinline__ bf16x8 ld_frag(const char* lbase, int row, int kk, int lane) {
    int cbyte = (kk * 64 + ((lane >> 4) * 16)) ^ ((row & 7) << 4);
    return *(const bf16x8*)(lbase + row * 128 + cbyte);
}

// -------- prep: Wq scaled by lin_w[(n%64)>>3]/sqrt(8) -> bf16; Wk -> bf16; bqs scaled --------
__global__ __launch_bounds__(256) void prep_w_kernel(
    const float* __restrict__ Wq, const float* __restrict__ bq,
    const float* __restrict__ Wk, const float* __restrict__ lin_w,
    unsigned short* __restrict__ Wqbf, unsigned short* __restrict__ Wkbf,
    float* __restrict__ bqs)
{
    const float invs = 0.35355339059327373f; // 1/sqrt(8)
    int idx4 = blockIdx.x * 256 + threadIdx.x;
    int i = idx4 * 4;
    if (blockIdx.z == 0) {
        int n = i / E_;                 // output channel (row of W)
        float w = lin_w[(n & 63) >> 3] * invs;
        float4 v = *(const float4*)(Wq + i);
        ushort4 o = make_ushort4(f2bf(v.x * w), f2bf(v.y * w), f2bf(v.z * w), f2bf(v.w * w));
        *(ushort4*)(Wqbf + i) = o;
        if (idx4 < E_) bqs[idx4] = bq[idx4] * (lin_w[(idx4 & 63) >> 3] * invs);
    } else {
        float4 v = *(const float4*)(Wk + i);
        ushort4 o = make_ushort4(f2bf(v.x), f2bf(v.y), f2bf(v.z), f2bf(v.w));
        *(ushort4*)(Wkbf + i) = o;
    }
}

// ---------------- proj: P[m,n] = sum_k X[m,k]*Wbf[n,k] + bias[n], bf16 out ----------------
// 64x64 tile, 2x2 waves of 32x32. X reg-staged fp32->bf16; W(bf16) via global_load_lds.
// 1D grid 768, XCD-chunked swizzle: 96 consecutive work-items per XCD (same z, 8 y x 12 x)
// -> X/W strips L2-resident per XCD.
__global__ __launch_bounds__(256) void proj_kernel(
    const float* __restrict__ q_in, const float* __restrict__ k_in,
    const unsigned short* __restrict__ Wqbf, const unsigned short* __restrict__ Wkbf,
    const float* __restrict__ bqs, const float* __restrict__ bk,
    unsigned short* __restrict__ qs, unsigned short* __restrict__ kp)
{
    __shared__ char lds[32768];   // X0 X1 (0,8K), W0 W1 (16K,24K)

    int lid = blockIdx.x;
    int swz = (lid & 7) * 96 + (lid >> 3);   // XCD-chunked (768 % 8 == 0, bijective)
    int z  = swz / 384;
    int rem = swz - z * 384;
    int ty = rem / 12, tx = rem - ty * 12;
    int tm = ty * 64, tn = tx * 64;

    const float* X          = z ? k_in : q_in;
    const unsigned short* W = z ? Wkbf : Wqbf;
    const float* bias       = z ? bk   : bqs;
    unsigned short* P       = z ? kp   : qs;

    int tid = threadIdx.x, lane = tid & 63, wid = tid >> 6;
    int wn = wid >> 1, wm = wid & 1;

    int c0 = tid,        r0 = c0 >> 3, g0 = ((c0 & 7) ^ (r0 & 7)) * 8;
    int c1 = 256 + tid,  r1 = c1 >> 3, g1 = ((c1 & 7) ^ (r1 & 7)) * 8;

    const float* Xg          = X + (size_t)tm * E_;
    const unsigned short* Wg = W + (size_t)tn * E_;

    float4 xv0, xv1, xv2, xv3;
#define LOADX(kb) { \
    const float* xs0 = Xg + r0 * E_ + (kb) + g0; xv0 = *(const float4*)xs0; xv1 = *(const float4*)(xs0 + 4); \
    const float* xs1 = Xg + r1 * E_ + (kb) + g1; xv2 = *(const float4*)xs1; xv3 = *(const float4*)(xs1 + 4); }
#define WRITEX(buf) { \
    char* xb = lds + (buf) * 8192; \
    *(u16x8*)(xb + c0 * 16) = pack8(xv0, xv1); \
    *(u16x8*)(xb + c1 * 16) = pack8(xv2, xv3); }
#define STAGEW(kb, buf) { \
    char* wb = lds + 16384 + (buf) * 8192; \
    __builtin_amdgcn_global_load_lds( \
        (const __attribute__((address_space(1))) void*)(Wg + (size_t)r0 * E_ + (kb) + g0), \
        (__attribute__((address_space(3))) void*)(wb + c0 * 16), 16, 0, 0); \
    __builtin_amdgcn_global_load_lds( \
        (const __attribute__((address_space(1))) void*)(Wg + (size_t)r1 * E_ + (kb) + g1), \
        (__attribute__((address_space(3))) void*)(wb + c1 * 16), 16, 0, 0); }

    // acc[nj][mi]: D rows = n (W dim), cols = m (X dim)  [swapped operands]
    f32x4 acc[2][2];
#pragma unroll
    for (int nj = 0; nj < 2; ++nj) {
        int n0 = tn + wn * 32 + nj * 16 + ((lane >> 4) << 2);
        float4 b4 = *(const float4*)(bias + n0);
#pragma unroll
        for (int mi = 0; mi < 2; ++mi)
            acc[nj][mi] = f32x4{b4.x, b4.y, b4.z, b4.w};
    }

#define COMPSTEP(buf) { \
    const char* Xc = lds + (buf) * 8192; \
    const char* Wc = lds + 16384 + (buf) * 8192; \
    _Pragma("unroll") \
    for (int kk = 0; kk < 2; ++kk) { \
        bf16x8 a0 = ld_frag(Wc, wn * 32 + (lane & 15), kk, lane); \
        bf16x8 a1 = ld_frag(Wc, wn * 32 + 16 + (lane & 15), kk, lane); \
        bf16x8 b0 = ld_frag(Xc, wm * 32 + (lane & 15), kk, lane); \
        bf16x8 b1 = ld_frag(Xc, wm * 32 + 16 + (lane & 15), kk, lane); \
        acc[0][0] = __builtin_amdgcn_mfma_f32_16x16x32_bf16(a0, b0, acc[0][0], 0, 0, 0); \
        acc[0][1] = __builtin_amdgcn_mfma_f32_16x16x32_bf16(a0, b1, acc[0][1], 0, 0, 0); \
        acc[1][0] = __builtin_amdgcn_mfma_f32_16x16x32_bf16(a1, b0, acc[1][0], 0, 0, 0); \
        acc[1][1] = __builtin_amdgcn_mfma_f32_16x16x32_bf16(a1, b1, acc[1][1], 0, 0, 0); \
    } }

    // prologue
    STAGEW(0, 0);
    LOADX(0);
    WRITEX(0);
    __syncthreads();
    int cur = 0;
#pragma unroll 2
    for (int t = 0; t < 11; ++t) {
        STAGEW((t + 1) * 64, cur ^ 1);   // async into next W buf
        LOADX((t + 1) * 64);             // prefetch next X to regs
        COMPSTEP(cur);
        WRITEX(cur ^ 1);
        __syncthreads();                 // drains W staging + X writes
        cur ^= 1;
    }
    COMPSTEP(cur);

#pragma unroll
    for (int nj = 0; nj < 2; ++nj)
#pragma unroll
        for (int mi = 0; mi < 2; ++mi) {
            int n0 = tn + wn * 32 + nj * 16 + ((lane >> 4) << 2);
            int m  = tm + wm * 32 + mi * 16 + (lane & 15);
            u16x4 pk;
            pk[0] = f2bf(acc[nj][mi][0]); pk[1] = f2bf(acc[nj][mi][1]);
            pk[2] = f2bf(acc[nj][mi][2]); pk[3] = f2bf(acc[nj][mi][3]);
            *(u16x4*)(P + (size_t)m * E_ + n0) = pk;
        }
#undef LOADX
#undef WRITEX
#undef STAGEW
#undef COMPSTEP
}

// ---------------- scores: per (b,h): out[i,j] = qs_i . kp_j + lin_b, fp32 out ----------------
// 1D grid 768, XCD-chunked swizzle (3 full heads per XCD chunk -> qs/kp L2-resident).
// Store reorder: compute sub0 -> barrier -> store sub0 (overlaps sub1 compute) -> sub1 -> store.
__global__ __launch_bounds__(256) void scores_kernel(
    const unsigned short* __restrict__ qs, const unsigned short* __restrict__ kp,
    const float* __restrict__ lin_b, float* __restrict__ out)
{
    __shared__ char lds[32768];   // Kb0, Kb1: 16KB each (128 rows x 64 bf16)

    int lid = blockIdx.x;
    int swz = (lid & 7) * 96 + (lid >> 3);   // 768 % 8 == 0, bijective
    int z   = swz >> 5;                      // 32 blocks per head
    int rem = swz & 31;
    int iy  = rem >> 2, jx = rem & 3;
    int b = z / H_, h = z - b * H_;

    int tid = threadIdx.x, lane = tid & 63, wid = tid >> 6;
    int wj = wid >> 1, wi = wid & 1;
    int ti = iy * 128, tj = jx * 256;

    const unsigned short* Qg = qs + (size_t)(b * S_) * E_ + h * 64;
    const unsigned short* Kg = kp + (size_t)(b * S_) * E_ + h * 64;

#define STAGEK(jbase, buf) { \
    char* lb = lds + (buf) * 16384; \
    _Pragma("unroll") \
    for (int pass = 0; pass < 4; ++pass) { \
        int c = pass * 256 + tid; \
        int row = c >> 3, cbg = (c & 7) ^ (row & 7); \
        __builtin_amdgcn_global_load_lds( \
            (const __attribute__((address_space(1))) void*)(Kg + (size_t)((jbase) + row) * E_ + cbg * 8), \
            (__attribute__((address_space(3))) void*)(lb + c * 16), 16, 0, 0); \
    } }

    bf16x8 qf[2][4];
    int qrow = ti + wi * 64 + (lane & 15);
#pragma unroll
    for (int ni = 0; ni < 4; ++ni)
#pragma unroll
        for (int kk = 0; kk < 2; ++kk)
            qf[kk][ni] = *(const bf16x8*)(Qg + (size_t)(qrow + ni * 16) * E_ + kk * 32 + ((lane >> 4) * 8));

    float lb0 = lin_b[0];
    float* O = out + ((size_t)z << 20);

    STAGEK(tj, 0);
    __syncthreads();                       // Kb0 ready
    STAGEK(tj + 128, 1);                   // prefetch second subtile (in flight)

    f32x4 acc[4][4];

    // ---- sub 0: compute ----
#pragma unroll
    for (int mj = 0; mj < 4; ++mj)
#pragma unroll
        for (int ni = 0; ni < 4; ++ni) acc[mj][ni] = f32x4{lb0, lb0, lb0, lb0};
#pragma unroll
    for (int kk = 0; kk < 2; ++kk) {
        bf16x8 a[4];
#pragma unroll
        for (int mj = 0; mj < 4; ++mj) a[mj] = ld_frag(lds, wj * 64 + mj * 16 + (lane & 15), kk, lane);
#pragma unroll
        for (int mj = 0; mj < 4; ++mj)
#pragma unroll
            for (int ni = 0; ni < 4; ++ni)
                acc[mj][ni] = __builtin_amdgcn_mfma_f32_16x16x32_bf16(a[mj], qf[kk][ni], acc[mj][ni], 0, 0, 0);
    }

    __syncthreads();                       // Kb1 staged; no stores outstanding yet

    // ---- sub 0: store (flies under sub1 compute) ----
#pragma unroll
    for (int mj = 0; mj < 4; ++mj)
#pragma unroll
        for (int ni = 0; ni < 4; ++ni) {
            int i  = ti + wi * 64 + ni * 16 + (lane & 15);
            int j0 = tj + wj * 64 + mj * 16 + ((lane >> 4) << 2);
            *(f32x4*)(O + (size_t)i * S_ + j0) = acc[mj][ni];
        }

    // ---- sub 1: compute ----
#pragma unroll
    for (int mj = 0; mj < 4; ++mj)
#pragma unroll
        for (int ni = 0; ni < 4; ++ni) acc[mj][ni] = f32x4{lb0, lb0, lb0, lb0};
#pragma unroll
    for (int kk = 0; kk < 2; ++kk) {
        bf16x8 a[4];
#pragma unroll
        for (int mj = 0; mj < 4; ++mj) a[mj] = ld_frag(lds + 16384, wj * 64 + mj * 16 + (lane & 15), kk, lane);
#pragma unroll
        for (int mj = 0; mj < 4; ++mj)
#pragma unroll
            for (int ni = 0; ni < 4; ++ni)
                acc[mj][ni] = __builtin_amdgcn_mfma_f32_16x16x32_bf16(a[mj], qf[kk][ni], acc[mj][ni], 0, 0, 0);
    }

    // ---- sub 1: store ----
#pragma unroll
    for (int mj = 0; mj < 4; ++mj)
#pragma unroll
        for (int ni = 0; ni < 4; ++ni) {
            int i  = ti + wi * 64 + ni * 16 + (lane & 15);
            int j0 = tj + 128 + wj * 64 + mj * 16 + ((lane >> 4) << 2);
            *(f32x4*)(O + (size_t)i * S_ + j0) = acc[mj][ni];
        }
#undef STAGEK
}

extern "C" void kernel_launch(void* const* d_in, const int* in_sizes, int n_in,
                              void* d_out, int out_size, void* d_ws, size_t ws_size,
                              hipStream_t stream)
{
    const float* k_in  = (const float*)d_in[0];
    const float* q_in  = (const float*)d_in[1];
    const float* Wq_w  = (const float*)d_in[2];
    const float* Wq_b  = (const float*)d_in[3];
    const float* Wk_w  = (const float*)d_in[4];
    const float* Wk_b  = (const float*)d_in[5];
    const float* lin_w = (const float*)d_in[6];
    const float* lin_b = (const float*)d_in[7];
    float* out = (float*)d_out;

    char* ws = (char*)d_ws;
    unsigned short* Wqbf = (unsigned short*)(ws + 0);
    unsigned short* Wkbf = (unsigned short*)(ws + 1179648);
    float*          bqs  = (float*)        (ws + 2359296);
    unsigned short* qsb  = (unsigned short*)(ws + 2362368);
    unsigned short* kpb  = (unsigned short*)(ws + 5508096);

    // 1) prep: Wq*(lin_w/sqrt8) -> bf16, Wk -> bf16, bq scaled
    prep_w_kernel<<<dim3(576, 1, 2), dim3(256), 0, stream>>>(Wq_w, Wq_b, Wk_w, lin_w, Wqbf, Wkbf, bqs);
    // 2) projections (XCD-chunked swizzle; W via global_load_lds bf16; X reg-staged fp32)
    proj_kernel<<<dim3(768), dim3(256), 0, stream>>>(q_in, k_in, Wqbf, Wkbf, bqs, Wk_b, qsb, kpb);
    // 3) scores (XCD-chunked swizzle; store-after-barrier overlap)
    scores_kernel<<<dim3(768), dim3(256), 0, stream>>>(qsb, kpb, lin_b, out);
}

// Round 9
// 42.111 us; speedup vs baseline: 2.2307x; 1.0767x over previous
//
#include <hip/hip_runtime.h>
#include <hip/hip_bf16.h>

#define S_ 1024
#define E_ 768
#define H_ 12

typedef __bf16  bf16x8 __attribute__((ext_vector_type(8)));
typedef float   f32x4  __attribute__((ext_vector_type(4)));
typedef unsigned short u16x4 __attribute__((ext_vector_type(4)));

__device__ __forceinline__ unsigned short f2bf(float f) {
    union { float f; unsigned u; } a; a.f = f;
    unsigned u = a.u;
    u += 0x7FFFu + ((u >> 16) & 1u);   // RNE
    return (unsigned short)(u >> 16);
}

// LDS tile layout: R rows x 64 bf16 (128B/row, 8x16B chunks).
// Physical chunk (row, cb) holds global chunk (row, cb ^ (row&7)).
__device__ __forceinline__ bf16x8 ld_frag(const char* lbase, int row, int kk, int lane) {
    int cbyte = (kk * 64 + ((lane >> 4) * 16)) ^ ((row & 7) << 4);
    return *(const bf16x8*)(lbase + row * 128 + cbyte);
}

// -------- prep: Wq*(lin_w/sqrt8)->bf16, Wk->bf16, bq scaled, q/k->bf16. One 1D launch. --------
__global__ __launch_bounds__(256) void prep_cast_kernel(
    const float* __restrict__ q_in, const float* __restrict__ k_in,
    const float* __restrict__ Wq, const float* __restrict__ Wk,
    const float* __restrict__ bq, const float* __restrict__ lin_w,
    unsigned short* __restrict__ Wqbf, unsigned short* __restrict__ Wkbf,
    unsigned short* __restrict__ qbf, unsigned short* __restrict__ kbf,
    float* __restrict__ bqs)
{
    const float invs = 0.35355339059327373f; // 1/sqrt(8)
    int u = blockIdx.x * 256 + threadIdx.x;  // float4 index
    if (u < 147456) {                        // Wq (scaled)
        int i = u * 4;
        int n = i / E_;
        float w = lin_w[(n & 63) >> 3] * invs;
        float4 v = *(const float4*)(Wq + i);
        *(ushort4*)(Wqbf + i) = make_ushort4(f2bf(v.x * w), f2bf(v.y * w), f2bf(v.z * w), f2bf(v.w * w));
        if (u < E_) bqs[u] = bq[u] * (lin_w[(u & 63) >> 3] * invs);
    } else if (u < 294912) {                 // Wk
        int i = (u - 147456) * 4;
        float4 v = *(const float4*)(Wk + i);
        *(ushort4*)(Wkbf + i) = make_ushort4(f2bf(v.x), f2bf(v.y), f2bf(v.z), f2bf(v.w));
    } else if (u < 688128) {                 // q
        int i = (u - 294912) * 4;
        float4 v = *(const float4*)(q_in + i);
        *(ushort4*)(qbf + i) = make_ushort4(f2bf(v.x), f2bf(v.y), f2bf(v.z), f2bf(v.w));
    } else {                                 // k
        int i = (u - 688128) * 4;
        float4 v = *(const float4*)(k_in + i);
        *(ushort4*)(kbf + i) = make_ushort4(f2bf(v.x), f2bf(v.y), f2bf(v.z), f2bf(v.w));
    }
}

// ---------------- proj: P[m,n] = sum_k X[m,k]*Wbf[n,k] + bias[n], bf16 out ----------------
// 64x64 tile, 2x2 waves of 32x32. BOTH operands bf16 via global_load_lds into a RING-3 LDS
// (16KB/buf), counted s_waitcnt vmcnt(4) + raw s_barrier — loads stay in flight across
// barriers (T3+T4); vmcnt(0) only in the 2-iter tail. XCD-chunked swizzle.
__global__ __launch_bounds__(256) void proj_kernel(
    const unsigned short* __restrict__ qbf, const unsigned short* __restrict__ kbf,
    const unsigned short* __restrict__ Wqbf, const unsigned short* __restrict__ Wkbf,
    const float* __restrict__ bqs, const float* __restrict__ bk,
    unsigned short* __restrict__ qs, unsigned short* __restrict__ kp)
{
    __shared__ char lds[3 * 16384];   // ring of 3 bufs: each {X 8K | W 8K}

    int lid = blockIdx.x;
    int swz = (lid & 7) * 96 + (lid >> 3);   // XCD-chunked (768 % 8 == 0, bijective)
    int z  = swz / 384;
    int rem = swz - z * 384;
    int ty = rem / 12, tx = rem - ty * 12;
    int tm = ty * 64, tn = tx * 64;

    const unsigned short* X = z ? kbf : qbf;
    const unsigned short* W = z ? Wkbf : Wqbf;
    const float* bias       = z ? bk   : bqs;
    unsigned short* P       = z ? kp   : qs;

    int tid = threadIdx.x, lane = tid & 63, wid = tid >> 6;
    int wn = wid >> 1, wm = wid & 1;

    int c0 = tid,        r0 = c0 >> 3, g0 = ((c0 & 7) ^ (r0 & 7)) * 8;
    int c1 = 256 + tid,  r1 = c1 >> 3, g1 = ((c1 & 7) ^ (r1 & 7)) * 8;

    const unsigned short* Xg = X + (size_t)tm * E_;
    const unsigned short* Wg = W + (size_t)tn * E_;

#define GLL(src, dst) __builtin_amdgcn_global_load_lds( \
        (const __attribute__((address_space(1))) void*)(src), \
        (__attribute__((address_space(3))) void*)(dst), 16, 0, 0)
#define STAGE(kb, buf) { \
    char* xb = lds + (buf) * 16384; \
    char* wb = xb + 8192; \
    GLL(Xg + (size_t)r0 * E_ + (kb) + g0, xb + c0 * 16); \
    GLL(Xg + (size_t)r1 * E_ + (kb) + g1, xb + c1 * 16); \
    GLL(Wg + (size_t)r0 * E_ + (kb) + g0, wb + c0 * 16); \
    GLL(Wg + (size_t)r1 * E_ + (kb) + g1, wb + c1 * 16); }

    f32x4 acc[2][2];
#pragma unroll
    for (int nj = 0; nj < 2; ++nj) {
        int n0 = tn + wn * 32 + nj * 16 + ((lane >> 4) << 2);
        float4 b4 = *(const float4*)(bias + n0);
#pragma unroll
        for (int mi = 0; mi < 2; ++mi)
            acc[nj][mi] = f32x4{b4.x, b4.y, b4.z, b4.w};
    }

#define COMPSTEP(buf) { \
    const char* Xc = lds + (buf) * 16384; \
    const char* Wc = Xc + 8192; \
    _Pragma("unroll") \
    for (int kk = 0; kk < 2; ++kk) { \
        bf16x8 a0 = ld_frag(Wc, wn * 32 + (lane & 15), kk, lane); \
        bf16x8 a1 = ld_frag(Wc, wn * 32 + 16 + (lane & 15), kk, lane); \
        bf16x8 b0 = ld_frag(Xc, wm * 32 + (lane & 15), kk, lane); \
        bf16x8 b1 = ld_frag(Xc, wm * 32 + 16 + (lane & 15), kk, lane); \
        acc[0][0] = __builtin_amdgcn_mfma_f32_16x16x32_bf16(a0, b0, acc[0][0], 0, 0, 0); \
        acc[0][1] = __builtin_amdgcn_mfma_f32_16x16x32_bf16(a0, b1, acc[0][1], 0, 0, 0); \
        acc[1][0] = __builtin_amdgcn_mfma_f32_16x16x32_bf16(a1, b0, acc[1][0], 0, 0, 0); \
        acc[1][1] = __builtin_amdgcn_mfma_f32_16x16x32_bf16(a1, b1, acc[1][1], 0, 0, 0); \
    } }

    // prologue: tiles 0,1 in flight
    STAGE(0, 0);
    STAGE(64, 1);

    int cur = 0, nxt = 2;
    for (int t = 0; t < 10; ++t) {
        asm volatile("s_waitcnt vmcnt(4)" ::: "memory");   // my tile-t loads done (4 newer)
        __builtin_amdgcn_s_barrier();                      // raw: no implicit drain
        __builtin_amdgcn_sched_barrier(0);
        STAGE((t + 2) * 64, nxt);                          // stage t+2 (after barrier: safe reuse)
        COMPSTEP(cur);
        cur = cur == 2 ? 0 : cur + 1;
        nxt = nxt == 2 ? 0 : nxt + 1;
    }
    // tail: t=10 (tile 11 still in flight), t=11
    asm volatile("s_waitcnt vmcnt(4)" ::: "memory");
    __builtin_amdgcn_s_barrier();
    __builtin_amdgcn_sched_barrier(0);
    COMPSTEP(cur);
    cur = cur == 2 ? 0 : cur + 1;
    asm volatile("s_waitcnt vmcnt(0)" ::: "memory");
    __builtin_amdgcn_s_barrier();
    __builtin_amdgcn_sched_barrier(0);
    COMPSTEP(cur);

#pragma unroll
    for (int nj = 0; nj < 2; ++nj)
#pragma unroll
        for (int mi = 0; mi < 2; ++mi) {
            int n0 = tn + wn * 32 + nj * 16 + ((lane >> 4) << 2);
            int m  = tm + wm * 32 + mi * 16 + (lane & 15);
            u16x4 pk;
            pk[0] = f2bf(acc[nj][mi][0]); pk[1] = f2bf(acc[nj][mi][1]);
            pk[2] = f2bf(acc[nj][mi][2]); pk[3] = f2bf(acc[nj][mi][3]);
            *(u16x4*)(P + (size_t)m * E_ + n0) = pk;
        }
#undef GLL
#undef STAGE
#undef COMPSTEP
}

// ---------------- scores: per (b,h): out[i,j] = qs_i . kp_j + lin_b, fp32 out ----------------
// (unchanged from R8: XCD-chunked swizzle; store-after-barrier overlap)
__global__ __launch_bounds__(256) void scores_kernel(
    const unsigned short* __restrict__ qs, const unsigned short* __restrict__ kp,
    const float* __restrict__ lin_b, float* __restrict__ out)
{
    __shared__ char lds[32768];   // Kb0, Kb1: 16KB each (128 rows x 64 bf16)

    int lid = blockIdx.x;
    int swz = (lid & 7) * 96 + (lid >> 3);   // 768 % 8 == 0, bijective
    int z   = swz >> 5;                      // 32 blocks per head
    int rem = swz & 31;
    int iy  = rem >> 2, jx = rem & 3;
    int b = z / H_, h = z - b * H_;

    int tid = threadIdx.x, lane = tid & 63, wid = tid >> 6;
    int wj = wid >> 1, wi = wid & 1;
    int ti = iy * 128, tj = jx * 256;

    const unsigned short* Qg = qs + (size_t)(b * S_) * E_ + h * 64;
    const unsigned short* Kg = kp + (size_t)(b * S_) * E_ + h * 64;

#define STAGEK(jbase, buf) { \
    char* lb = lds + (buf) * 16384; \
    _Pragma("unroll") \
    for (int pass = 0; pass < 4; ++pass) { \
        int c = pass * 256 + tid; \
        int row = c >> 3, cbg = (c & 7) ^ (row & 7); \
        __builtin_amdgcn_global_load_lds( \
            (const __attribute__((address_space(1))) void*)(Kg + (size_t)((jbase) + row) * E_ + cbg * 8), \
            (__attribute__((address_space(3))) void*)(lb + c * 16), 16, 0, 0); \
    } }

    bf16x8 qf[2][4];
    int qrow = ti + wi * 64 + (lane & 15);
#pragma unroll
    for (int ni = 0; ni < 4; ++ni)
#pragma unroll
        for (int kk = 0; kk < 2; ++kk)
            qf[kk][ni] = *(const bf16x8*)(Qg + (size_t)(qrow + ni * 16) * E_ + kk * 32 + ((lane >> 4) * 8));

    float lb0 = lin_b[0];
    float* O = out + ((size_t)z << 20);

    STAGEK(tj, 0);
    __syncthreads();                       // Kb0 ready
    STAGEK(tj + 128, 1);                   // prefetch second subtile (in flight)

    f32x4 acc[4][4];

    // ---- sub 0: compute ----
#pragma unroll
    for (int mj = 0; mj < 4; ++mj)
#pragma unroll
        for (int ni = 0; ni < 4; ++ni) acc[mj][ni] = f32x4{lb0, lb0, lb0, lb0};
#pragma unroll
    for (int kk = 0; kk < 2; ++kk) {
        bf16x8 a[4];
#pragma unroll
        for (int mj = 0; mj < 4; ++mj) a[mj] = ld_frag(lds, wj * 64 + mj * 16 + (lane & 15), kk, lane);
#pragma unroll
        for (int mj = 0; mj < 4; ++mj)
#pragma unroll
            for (int ni = 0; ni < 4; ++ni)
                acc[mj][ni] = __builtin_amdgcn_mfma_f32_16x16x32_bf16(a[mj], qf[kk][ni], acc[mj][ni], 0, 0, 0);
    }

    __syncthreads();                       // Kb1 staged; no stores outstanding yet

    // ---- sub 0: store (flies under sub1 compute) ----
#pragma unroll
    for (int mj = 0; mj < 4; ++mj)
#pragma unroll
        for (int ni = 0; ni < 4; ++ni) {
            int i  = ti + wi * 64 + ni * 16 + (lane & 15);
            int j0 = tj + wj * 64 + mj * 16 + ((lane >> 4) << 2);
            *(f32x4*)(O + (size_t)i * S_ + j0) = acc[mj][ni];
        }

    // ---- sub 1: compute ----
#pragma unroll
    for (int mj = 0; mj < 4; ++mj)
#pragma unroll
        for (int ni = 0; ni < 4; ++ni) acc[mj][ni] = f32x4{lb0, lb0, lb0, lb0};
#pragma unroll
    for (int kk = 0; kk < 2; ++kk) {
        bf16x8 a[4];
#pragma unroll
        for (int mj = 0; mj < 4; ++mj) a[mj] = ld_frag(lds + 16384, wj * 64 + mj * 16 + (lane & 15), kk, lane);
#pragma unroll
        for (int mj = 0; mj < 4; ++mj)
#pragma unroll
            for (int ni = 0; ni < 4; ++ni)
                acc[mj][ni] = __builtin_amdgcn_mfma_f32_16x16x32_bf16(a[mj], qf[kk][ni], acc[mj][ni], 0, 0, 0);
    }

    // ---- sub 1: store ----
#pragma unroll
    for (int mj = 0; mj < 4; ++mj)
#pragma unroll
        for (int ni = 0; ni < 4; ++ni) {
            int i  = ti + wi * 64 + ni * 16 + (lane & 15);
            int j0 = tj + 128 + wj * 64 + mj * 16 + ((lane >> 4) << 2);
            *(f32x4*)(O + (size_t)i * S_ + j0) = acc[mj][ni];
        }
#undef STAGEK
}

extern "C" void kernel_launch(void* const* d_in, const int* in_sizes, int n_in,
                              void* d_out, int out_size, void* d_ws, size_t ws_size,
                              hipStream_t stream)
{
    const float* k_in  = (const float*)d_in[0];
    const float* q_in  = (const float*)d_in[1];
    const float* Wq_w  = (const float*)d_in[2];
    const float* Wq_b  = (const float*)d_in[3];
    const float* Wk_w  = (const float*)d_in[4];
    const float* Wk_b  = (const float*)d_in[5];
    const float* lin_w = (const float*)d_in[6];
    const float* lin_b = (const float*)d_in[7];
    float* out = (float*)d_out;

    char* ws = (char*)d_ws;
    unsigned short* Wqbf = (unsigned short*)(ws + 0);
    unsigned short* Wkbf = (unsigned short*)(ws + 1179648);
    float*          bqs  = (float*)        (ws + 2359296);
    unsigned short* qbf  = (unsigned short*)(ws + 2362368);
    unsigned short* kbf  = (unsigned short*)(ws + 5508096);
    unsigned short* qsb  = (unsigned short*)(ws + 8653824);
    unsigned short* kpb  = (unsigned short*)(ws + 11799552);

    // 1) prep+cast (one 1D launch): Wq scaled->bf16, Wk->bf16, bqs, q->bf16, k->bf16
    prep_cast_kernel<<<dim3(4224), dim3(256), 0, stream>>>(q_in, k_in, Wq_w, Wk_w, Wq_b, lin_w,
                                                           Wqbf, Wkbf, qbf, kbf, bqs);
    // 2) projections: counted-vmcnt ring-3 pipeline, all-bf16 global_load_lds
    proj_kernel<<<dim3(768), dim3(256), 0, stream>>>(qbf, kbf, Wqbf, Wkbf, bqs, Wk_b, qsb, kpb);
    // 3) scores (unchanged R8)
    scores_kernel<<<dim3(768), dim3(256), 0, stream>>>(qsb, kpb, lin_b, out);
}